// Round 13
// baseline (63.599 us; speedup 1.0000x reference)
//
#include <hip/hip_runtime.h>

// Problem constants (fixed by setup_inputs)
#define N_BATCH 32
#define C_IN    64
#define H_IN    32
#define W_IN    32
#define C_OUT   512
#define H_OUT   32
#define W_OUT   32

#define PH      34                 // padded plane height/width
#define PSTRIDE (PH * PH)          // 1156 floats per padded plane

typedef float f32x4 __attribute__((ext_vector_type(4)));

__device__ __forceinline__ void op_coeffs(int i, float& c0, float& c1, float& c2, float& c3) {
    constexpr float T[16][4] = {
        {0.f,0.f,0.f,0.f}, {0.f,0.f,0.f,1.f}, {0.f,1.f,0.f,-1.f}, {0.f,1.f,0.f,0.f},
        {0.f,0.f,1.f,-1.f}, {0.f,0.f,1.f,0.f}, {0.f,1.f,1.f,-2.f}, {0.f,1.f,1.f,-1.f},
        {1.f,-1.f,-1.f,1.f}, {1.f,-1.f,-1.f,2.f}, {1.f,0.f,-1.f,0.f}, {1.f,0.f,-1.f,1.f},
        {1.f,-1.f,0.f,0.f}, {1.f,-1.f,0.f,1.f}, {1.f,0.f,0.f,-1.f}, {1.f,0.f,0.f,0.f}
    };
    c0 = T[i][0]; c1 = T[i][1]; c2 = T[i][2]; c3 = T[i][3];
}

// ---------- prep: blocks 0..7 -> coef table; blocks 8..2055 -> padded x ----------
__global__ __launch_bounds__(256)
void prep_kernel(const float* __restrict__ x,
                 const float* __restrict__ weights,
                 f32x4* __restrict__ coef,
                 float* __restrict__ xpad) {
    const int blk = blockIdx.x;
    if (blk < 8) {
        const int idx = blk * 256 + threadIdx.x;       // (c*4+p), 0..2047
        const float* w = weights + idx * 16;
        float v[16];
        float m = -3.402823466e+38f;
        #pragma unroll
        for (int i = 0; i < 16; ++i) { v[i] = w[i]; m = fmaxf(m, v[i]); }
        float ssum = 0.f;
        #pragma unroll
        for (int i = 0; i < 16; ++i) { v[i] = __expf(v[i] - m); ssum += v[i]; }
        const float inv = 1.0f / ssum;
        float c0 = 0.f, c1 = 0.f, c2 = 0.f, c3 = 0.f;
        #pragma unroll
        for (int i = 0; i < 16; ++i) {
            float t0, t1, t2, t3;
            op_coeffs(i, t0, t1, t2, t3);
            c0 = fmaf(v[i], t0, c0);
            c1 = fmaf(v[i], t1, c1);
            c2 = fmaf(v[i], t2, c2);
            c3 = fmaf(v[i], t3, c3);
        }
        f32x4 out; out.x = c0 * inv; out.y = c1 * inv; out.z = c2 * inv; out.w = c3 * inv;
        coef[idx] = out;
    } else {
        const int p = blk - 8;                          // plane = n*64 + ch, 0..2047
        const float* __restrict__ src = x    + (size_t)p * (H_IN * W_IN);
        float*       __restrict__ dst = xpad + (size_t)p * PSTRIDE;
        for (int e = threadIdx.x; e < PSTRIDE; e += 256) {
            const int r  = e / PH;                      // 0..33 (magic-mul)
            const int cc = e - r * PH;                  // 0..33
            const unsigned ri = (unsigned)(r - 1), ci = (unsigned)(cc - 1);
            float v = (ri < W_IN && ci < W_IN) ? src[ri * W_IN + ci] : 0.0f;
            dst[e] = v;
        }
    }
}

// ---------- main: ALL 32 loads issued before any consumption; NORMAL stores ----------
// A/B vs R12: (1) 4x load ILP per wave (32 outstanding global_loads before the
// first s_waitcnt) to break marginal latency hiding; (2) regular cached stores
// instead of nontemporal (fills hit 7 TB/s with cached stores; NT was never
// A/B'd and bypasses L2's write buffering).
__global__ __launch_bounds__(256)
void conv_main_padded(const float* __restrict__ xpad,
                      const f32x4* __restrict__ coef,
                      const int*   __restrict__ sel,
                      float* __restrict__ y) {
    const int c = blockIdx.x;   // C_OUT
    const int n = blockIdx.y;   // N

    const int s0 = sel[c * 8 + 0], s1 = sel[c * 8 + 1];
    const int s2 = sel[c * 8 + 2], s3 = sel[c * 8 + 3];
    const int s4 = sel[c * 8 + 4], s5 = sel[c * 8 + 5];
    const int s6 = sel[c * 8 + 6], s7 = sel[c * 8 + 7];
    const f32x4 cf0 = coef[c * 4 + 0];
    const f32x4 cf1 = coef[c * 4 + 1];
    const f32x4 cf2 = coef[c * 4 + 2];
    const f32x4 cf3 = coef[c * 4 + 3];

    const float* __restrict__ pb = xpad + (size_t)n * (C_IN * PSTRIDE);
    #define PLANE(s) (pb + ((s) >> 16) * PSTRIDE + (((s) >> 8) & 0xff) * PH + ((s) & 0xff))
    const float* __restrict__ p0 = PLANE(s0);
    const float* __restrict__ p1 = PLANE(s1);
    const float* __restrict__ p2 = PLANE(s2);
    const float* __restrict__ p3 = PLANE(s3);
    const float* __restrict__ p4 = PLANE(s4);
    const float* __restrict__ p5 = PLANE(s5);
    const float* __restrict__ p6 = PLANE(s6);
    const float* __restrict__ p7 = PLANE(s7);
    #undef PLANE

    f32x4* __restrict__ yv = reinterpret_cast<f32x4*>(y) +
                             (size_t)(n * C_OUT + c) * (H_OUT * W_OUT);

    const int tid   = threadIdx.x;
    const int poff0 = (tid >> 5) * PH + (tid & 31);

    // Phase 1: issue all 32 independent loads (static indices -> registers).
    float va[4][8];
    #pragma unroll
    for (int k = 0; k < 4; ++k) {
        const int o = poff0 + k * (8 * PH);
        va[k][0] = p0[o]; va[k][1] = p1[o];
        va[k][2] = p2[o]; va[k][3] = p3[o];
        va[k][4] = p4[o]; va[k][5] = p5[o];
        va[k][6] = p6[o]; va[k][7] = p7[o];
    }

    // Phase 2: arithmetic + 4 normal dwordx4 stores.
    #pragma unroll
    for (int k = 0; k < 4; ++k) {
        const float a0 = va[k][0], b0 = va[k][1];
        const float a1 = va[k][2], b1 = va[k][3];
        const float a2 = va[k][4], b2 = va[k][5];
        const float a3 = va[k][6], b3 = va[k][7];
        f32x4 out;
        out.x = fmaf(cf0.w * a0, b0, fmaf(cf0.y, a0, fmaf(cf0.z, b0, cf0.x)));
        out.y = fmaf(cf1.w * a1, b1, fmaf(cf1.y, a1, fmaf(cf1.z, b1, cf1.x)));
        out.z = fmaf(cf2.w * a2, b2, fmaf(cf2.y, a2, fmaf(cf2.z, b2, cf2.x)));
        out.w = fmaf(cf3.w * a3, b3, fmaf(cf3.y, a3, fmaf(cf3.z, b3, cf3.x)));
        yv[tid + k * 256] = out;   // normal cached store (A/B vs NT)
    }
}

// ---------- fused fallback (if d_ws too small) — proven R8 structure ----------
__device__ __forceinline__ float gather_x(const float* __restrict__ x,
                                          int nbase, int s, int oh, int ow) {
    int ch = (s >> 16) & 0xffff;
    int ry = (s >> 8) & 0xff;
    int rx = s & 0xff;
    int r = oh + ry - 1;
    int c = ow + rx - 1;
    bool ok = ((unsigned)r < (unsigned)H_IN) && ((unsigned)c < (unsigned)W_IN);
    return ok ? x[nbase + ch * (H_IN * W_IN) + r * W_IN + c] : 0.0f;
}

__global__ __launch_bounds__(256)
void conv_fused_kernel(const float* __restrict__ x,
                       const float* __restrict__ weights,
                       const int*   __restrict__ sel,
                       float* __restrict__ y) {
    const int c = blockIdx.x;
    const int n = blockIdx.y;

    __shared__ float4 s_coef[4];
    __shared__ int    s_sel[8];

    if (threadIdx.x < 8) s_sel[threadIdx.x] = sel[c * 8 + threadIdx.x];
    if (threadIdx.x < 4) {
        const int p = threadIdx.x;
        const float* w = weights + (c * 4 + p) * 16;
        float v[16];
        float m = -3.402823466e+38f;
        #pragma unroll
        for (int i = 0; i < 16; ++i) { v[i] = w[i]; m = fmaxf(m, v[i]); }
        float ssum = 0.f;
        #pragma unroll
        for (int i = 0; i < 16; ++i) { v[i] = __expf(v[i] - m); ssum += v[i]; }
        const float inv = 1.0f / ssum;
        float c0 = 0.f, c1 = 0.f, c2 = 0.f, c3 = 0.f;
        #pragma unroll
        for (int i = 0; i < 16; ++i) {
            float t0, t1, t2, t3;
            op_coeffs(i, t0, t1, t2, t3);
            c0 = fmaf(v[i], t0, c0);
            c1 = fmaf(v[i], t1, c1);
            c2 = fmaf(v[i], t2, c2);
            c3 = fmaf(v[i], t3, c3);
        }
        s_coef[p] = make_float4(c0 * inv, c1 * inv, c2 * inv, c3 * inv);
    }
    __syncthreads();

    const int nbase = n * (C_IN * H_IN * W_IN);
    f32x4* __restrict__ yv = reinterpret_cast<f32x4*>(y) +
                             (size_t)(n * C_OUT + c) * (H_OUT * W_OUT);

    const float4 cf0 = s_coef[0], cf1 = s_coef[1], cf2 = s_coef[2], cf3 = s_coef[3];
    const int sl0 = s_sel[0], sl1 = s_sel[1], sl2 = s_sel[2], sl3 = s_sel[3];
    const int sl4 = s_sel[4], sl5 = s_sel[5], sl6 = s_sel[6], sl7 = s_sel[7];

    #pragma unroll
    for (int k = 0; k < 4; ++k) {
        const int pos = threadIdx.x + k * 256;
        const int oh = pos >> 5;
        const int ow = pos & 31;
        float a, b;
        f32x4 out;
        a = gather_x(x, nbase, sl0, oh, ow);
        b = gather_x(x, nbase, sl1, oh, ow);
        out.x = fmaf(cf0.w * a, b, fmaf(cf0.y, a, fmaf(cf0.z, b, cf0.x)));
        a = gather_x(x, nbase, sl2, oh, ow);
        b = gather_x(x, nbase, sl3, oh, ow);
        out.y = fmaf(cf1.w * a, b, fmaf(cf1.y, a, fmaf(cf1.z, b, cf1.x)));
        a = gather_x(x, nbase, sl4, oh, ow);
        b = gather_x(x, nbase, sl5, oh, ow);
        out.z = fmaf(cf2.w * a, b, fmaf(cf2.y, a, fmaf(cf2.z, b, cf2.x)));
        a = gather_x(x, nbase, sl6, oh, ow);
        b = gather_x(x, nbase, sl7, oh, ow);
        out.w = fmaf(cf3.w * a, b, fmaf(cf3.y, a, fmaf(cf3.z, b, cf3.x)));
        yv[pos] = out;
    }
}

extern "C" void kernel_launch(void* const* d_in, const int* in_sizes, int n_in,
                              void* d_out, int out_size, void* d_ws, size_t ws_size,
                              hipStream_t stream) {
    const float* x       = (const float*)d_in[0];
    const float* weights = (const float*)d_in[1];
    const int*   sel     = (const int*)d_in[2];
    float* y             = (float*)d_out;

    const size_t coef_bytes = (size_t)C_OUT * 4 * sizeof(f32x4);            // 32 KB
    const size_t pad_bytes  = (size_t)N_BATCH * C_IN * PSTRIDE * sizeof(float); // ~9.5 MB
    dim3 grid(C_OUT, N_BATCH);

    if (ws_size >= coef_bytes + pad_bytes) {
        f32x4* coef = (f32x4*)d_ws;
        float* xpad = (float*)((char*)d_ws + coef_bytes);
        prep_kernel<<<dim3(8 + N_BATCH * C_IN), 256, 0, stream>>>(x, weights, coef, xpad);
        conv_main_padded<<<grid, 256, 0, stream>>>(xpad, coef, sel, y);
    } else {
        conv_fused_kernel<<<grid, 256, 0, stream>>>(x, weights, sel, y);
    }
}

// Round 14
// 62.854 us; speedup vs baseline: 1.0118x; 1.0118x over previous
//
#include <hip/hip_runtime.h>

// Problem constants (fixed by setup_inputs)
#define N_BATCH 32
#define C_IN    64
#define H_IN    32
#define W_IN    32
#define C_OUT   512
#define H_OUT   32
#define W_OUT   32

#define N_PER_BLOCK 8   // batch images per block: amortize prologue 8x

typedef float f32x4 __attribute__((ext_vector_type(4)));

__device__ __forceinline__ void op_coeffs(int i, float& c0, float& c1, float& c2, float& c3) {
    constexpr float T[16][4] = {
        {0.f,0.f,0.f,0.f}, {0.f,0.f,0.f,1.f}, {0.f,1.f,0.f,-1.f}, {0.f,1.f,0.f,0.f},
        {0.f,0.f,1.f,-1.f}, {0.f,0.f,1.f,0.f}, {0.f,1.f,1.f,-2.f}, {0.f,1.f,1.f,-1.f},
        {1.f,-1.f,-1.f,1.f}, {1.f,-1.f,-1.f,2.f}, {1.f,0.f,-1.f,0.f}, {1.f,0.f,-1.f,1.f},
        {1.f,-1.f,0.f,0.f}, {1.f,-1.f,0.f,1.f}, {1.f,0.f,0.f,-1.f}, {1.f,0.f,0.f,0.f}
    };
    c0 = T[i][0]; c1 = T[i][1]; c2 = T[i][2]; c3 = T[i][3];
}

// ---------- kernel 1: coefficient table (2048 entries -> d_ws, 32 KB) ----------
__global__ __launch_bounds__(256)
void coef_kernel(const float* __restrict__ weights, f32x4* __restrict__ coef) {
    const int idx = blockIdx.x * 256 + threadIdx.x;   // (c*4 + p), 0..2047
    const float* w = weights + idx * 16;
    float v[16];
    float m = -3.402823466e+38f;
    #pragma unroll
    for (int i = 0; i < 16; ++i) { v[i] = w[i]; m = fmaxf(m, v[i]); }
    float ssum = 0.f;
    #pragma unroll
    for (int i = 0; i < 16; ++i) { v[i] = __expf(v[i] - m); ssum += v[i]; }
    const float inv = 1.0f / ssum;
    float c0 = 0.f, c1 = 0.f, c2 = 0.f, c3 = 0.f;
    #pragma unroll
    for (int i = 0; i < 16; ++i) {
        float t0, t1, t2, t3;
        op_coeffs(i, t0, t1, t2, t3);
        c0 = fmaf(v[i], t0, c0);
        c1 = fmaf(v[i], t1, c1);
        c2 = fmaf(v[i], t2, c2);
        c3 = fmaf(v[i], t3, c3);
    }
    f32x4 out; out.x = c0 * inv; out.y = c1 * inv; out.z = c2 * inv; out.w = c3 * inv;
    coef[idx] = out;
}

__device__ __forceinline__ float gather_x(const float* __restrict__ x,
                                          int nbase, int s, int oh, int ow) {
    int ch = (s >> 16) & 0xffff;
    int ry = (s >> 8) & 0xff;
    int rx = s & 0xff;
    int r = oh + ry - 1;          // PAD_H = 1
    int c = ow + rx - 1;          // PAD_W = 1
    bool ok = ((unsigned)r < (unsigned)H_IN) && ((unsigned)c < (unsigned)W_IN);
    return ok ? x[nbase + ch * (H_IN * W_IN) + r * W_IN + c] : 0.0f;
}

// ---------- kernel 2: main stream — R10 body, 8 batch images per block ----------
// sel/coef are block-uniform scalar loads done ONCE; the n-loop reuses them.
// 2048 blocks x 4 waves = 8192 waves = exactly one full-chip residency
// generation (256 CU x 32 waves): prologue amortized 8x, no dispatch churn.
__global__ __launch_bounds__(256)
void conv_main_kernel(const float* __restrict__ x,
                      const f32x4* __restrict__ coef,
                      const int*   __restrict__ sel,
                      float* __restrict__ y) {
    const int c  = blockIdx.x;                 // C_OUT
    const int n0 = blockIdx.y * N_PER_BLOCK;   // first batch image

    const int sl0 = sel[c * 8 + 0], sl1 = sel[c * 8 + 1];
    const int sl2 = sel[c * 8 + 2], sl3 = sel[c * 8 + 3];
    const int sl4 = sel[c * 8 + 4], sl5 = sel[c * 8 + 5];
    const int sl6 = sel[c * 8 + 6], sl7 = sel[c * 8 + 7];
    const f32x4 cf0 = coef[c * 4 + 0];
    const f32x4 cf1 = coef[c * 4 + 1];
    const f32x4 cf2 = coef[c * 4 + 2];
    const f32x4 cf3 = coef[c * 4 + 3];

    for (int nn = 0; nn < N_PER_BLOCK; ++nn) {
        const int n = n0 + nn;
        const int nbase = n * (C_IN * H_IN * W_IN);
        f32x4* __restrict__ yv = reinterpret_cast<f32x4*>(y) +
                                 (size_t)(n * C_OUT + c) * (H_OUT * W_OUT);

        #pragma unroll
        for (int k = 0; k < 4; ++k) {
            const int pos = threadIdx.x + k * 256;   // 0..1023
            const int oh = pos >> 5;
            const int ow = pos & 31;

            float a, b;
            f32x4 out;

            a = gather_x(x, nbase, sl0, oh, ow);
            b = gather_x(x, nbase, sl1, oh, ow);
            out.x = fmaf(cf0.w * a, b, fmaf(cf0.y, a, fmaf(cf0.z, b, cf0.x)));

            a = gather_x(x, nbase, sl2, oh, ow);
            b = gather_x(x, nbase, sl3, oh, ow);
            out.y = fmaf(cf1.w * a, b, fmaf(cf1.y, a, fmaf(cf1.z, b, cf1.x)));

            a = gather_x(x, nbase, sl4, oh, ow);
            b = gather_x(x, nbase, sl5, oh, ow);
            out.z = fmaf(cf2.w * a, b, fmaf(cf2.y, a, fmaf(cf2.z, b, cf2.x)));

            a = gather_x(x, nbase, sl6, oh, ow);
            b = gather_x(x, nbase, sl7, oh, ow);
            out.w = fmaf(cf3.w * a, b, fmaf(cf3.y, a, fmaf(cf3.z, b, cf3.x)));

            __builtin_nontemporal_store(out, &yv[pos]);
        }
    }
}

// ---------- fused fallback (only if d_ws too small) — proven R8 structure ----------
__global__ __launch_bounds__(256)
void conv_fused_kernel(const float* __restrict__ x,
                       const float* __restrict__ weights,
                       const int*   __restrict__ sel,
                       float* __restrict__ y) {
    const int c = blockIdx.x;
    const int n = blockIdx.y;

    __shared__ float4 s_coef[4];
    __shared__ int    s_sel[8];

    if (threadIdx.x < 8) s_sel[threadIdx.x] = sel[c * 8 + threadIdx.x];
    if (threadIdx.x < 4) {
        const int p = threadIdx.x;
        const float* w = weights + (c * 4 + p) * 16;
        float v[16];
        float m = -3.402823466e+38f;
        #pragma unroll
        for (int i = 0; i < 16; ++i) { v[i] = w[i]; m = fmaxf(m, v[i]); }
        float ssum = 0.f;
        #pragma unroll
        for (int i = 0; i < 16; ++i) { v[i] = __expf(v[i] - m); ssum += v[i]; }
        const float inv = 1.0f / ssum;
        float c0 = 0.f, c1 = 0.f, c2 = 0.f, c3 = 0.f;
        #pragma unroll
        for (int i = 0; i < 16; ++i) {
            float t0, t1, t2, t3;
            op_coeffs(i, t0, t1, t2, t3);
            c0 = fmaf(v[i], t0, c0);
            c1 = fmaf(v[i], t1, c1);
            c2 = fmaf(v[i], t2, c2);
            c3 = fmaf(v[i], t3, c3);
        }
        s_coef[p] = make_float4(c0 * inv, c1 * inv, c2 * inv, c3 * inv);
    }
    __syncthreads();

    const int nbase = n * (C_IN * H_IN * W_IN);
    f32x4* __restrict__ yv = reinterpret_cast<f32x4*>(y) +
                             (size_t)(n * C_OUT + c) * (H_OUT * W_OUT);

    const float4 cf0 = s_coef[0], cf1 = s_coef[1], cf2 = s_coef[2], cf3 = s_coef[3];
    const int sl0 = s_sel[0], sl1 = s_sel[1], sl2 = s_sel[2], sl3 = s_sel[3];
    const int sl4 = s_sel[4], sl5 = s_sel[5], sl6 = s_sel[6], sl7 = s_sel[7];

    #pragma unroll
    for (int k = 0; k < 4; ++k) {
        const int pos = threadIdx.x + k * 256;
        const int oh = pos >> 5;
        const int ow = pos & 31;
        float a, b;
        f32x4 out;
        a = gather_x(x, nbase, sl0, oh, ow);
        b = gather_x(x, nbase, sl1, oh, ow);
        out.x = fmaf(cf0.w * a, b, fmaf(cf0.y, a, fmaf(cf0.z, b, cf0.x)));
        a = gather_x(x, nbase, sl2, oh, ow);
        b = gather_x(x, nbase, sl3, oh, ow);
        out.y = fmaf(cf1.w * a, b, fmaf(cf1.y, a, fmaf(cf1.z, b, cf1.x)));
        a = gather_x(x, nbase, sl4, oh, ow);
        b = gather_x(x, nbase, sl5, oh, ow);
        out.z = fmaf(cf2.w * a, b, fmaf(cf2.y, a, fmaf(cf2.z, b, cf2.x)));
        a = gather_x(x, nbase, sl6, oh, ow);
        b = gather_x(x, nbase, sl7, oh, ow);
        out.w = fmaf(cf3.w * a, b, fmaf(cf3.y, a, fmaf(cf3.z, b, cf3.x)));
        __builtin_nontemporal_store(out, &yv[pos]);
    }
}

extern "C" void kernel_launch(void* const* d_in, const int* in_sizes, int n_in,
                              void* d_out, int out_size, void* d_ws, size_t ws_size,
                              hipStream_t stream) {
    const float* x       = (const float*)d_in[0];
    const float* weights = (const float*)d_in[1];
    const int*   sel     = (const int*)d_in[2];
    float* y             = (float*)d_out;

    const size_t coef_bytes = (size_t)C_OUT * 4 * sizeof(f32x4);   // 32 KB

    if (ws_size >= coef_bytes) {
        f32x4* coef = (f32x4*)d_ws;
        coef_kernel<<<dim3(8), 256, 0, stream>>>(weights, coef);
        conv_main_kernel<<<dim3(C_OUT, N_BATCH / N_PER_BLOCK), 256, 0, stream>>>(x, coef, sel, y);
    } else {
        conv_fused_kernel<<<dim3(C_OUT, N_BATCH), 256, 0, stream>>>(x, weights, sel, y);
    }
}

// Round 15
// 61.077 us; speedup vs baseline: 1.0413x; 1.0291x over previous
//
#include <hip/hip_runtime.h>

// Problem constants (fixed by setup_inputs)
#define N_BATCH 32
#define C_IN    64
#define H_IN    32
#define W_IN    32
#define C_OUT   512
#define H_OUT   32
#define W_OUT   32

typedef float f32x4 __attribute__((ext_vector_type(4)));

__device__ __forceinline__ float gather_x(const float* __restrict__ x,
                                          int nbase, int s, int oh, int ow) {
    int ch = (s >> 16) & 0xffff;
    int ry = (s >> 8) & 0xff;
    int rx = s & 0xff;
    int r = oh + ry - 1;          // PAD_H = 1
    int c = ow + rx - 1;          // PAD_W = 1
    bool ok = ((unsigned)r < (unsigned)H_IN) && ((unsigned)c < (unsigned)W_IN);
    return ok ? x[nbase + ch * (H_IN * W_IN) + r * W_IN + c] : 0.0f;
}

// Single kernel, single dispatch: the softmax-coef prologue is computed
// WAVE-PARALLEL in registers (no LDS, no __syncthreads, no second kernel).
// Lane l of each wave owns (p = l>>4, i = l&15); 16-lane shfl_xor butterflies
// produce softmax and the coef dot-product. OP_COEFFS[i] is synthesized from
// the bits of i (it is exactly the multilinear expansion of the 16 two-input
// boolean gates): f00=(i>>3)&1, f01=(i>>2)&1, f10=(i>>1)&1, f11=i&1;
// k0=f00, ka=f10-f00, kb=f01-f00, kab=f11-f10-f01+f00.  (Verified: all 16 rows.)
__global__ __launch_bounds__(256)
void conv_logic_kernel(const float* __restrict__ x,
                       const float* __restrict__ weights,
                       const int*   __restrict__ sel,
                       float* __restrict__ y) {
    const int c = blockIdx.x;   // C_OUT
    const int n = blockIdx.y;   // N
    const int lane = threadIdx.x & 63;

    // ---- wave-parallel coefficient computation (once per wave) ----
    const int i = lane & 15;                       // softmax element
    const float w = weights[c * 64 + lane];        // (c*4+p)*16+i == c*64+lane (coalesced)

    float m = w;                                   // 16-lane group max
    m = fmaxf(m, __shfl_xor(m, 1));
    m = fmaxf(m, __shfl_xor(m, 2));
    m = fmaxf(m, __shfl_xor(m, 4));
    m = fmaxf(m, __shfl_xor(m, 8));
    const float v = __expf(w - m);
    float ssum = v;                                // 16-lane group sum
    ssum += __shfl_xor(ssum, 1);
    ssum += __shfl_xor(ssum, 2);
    ssum += __shfl_xor(ssum, 4);
    ssum += __shfl_xor(ssum, 8);
    const float inv = 1.0f / ssum;

    const float f00 = (float)((i >> 3) & 1);
    const float f01 = (float)((i >> 2) & 1);
    const float f10 = (float)((i >> 1) & 1);
    const float f11 = (float)(i & 1);

    float t0 = v * f00;                            // k0 contribution
    float t1 = v * (f10 - f00);                    // ka
    float t2 = v * (f01 - f00);                    // kb
    float t3 = v * (f11 - f10 - f01 + f00);        // kab

    #define GSUM(t) t += __shfl_xor(t, 1); t += __shfl_xor(t, 2); \
                    t += __shfl_xor(t, 4); t += __shfl_xor(t, 8);
    GSUM(t0) GSUM(t1) GSUM(t2) GSUM(t3)
    #undef GSUM
    t0 *= inv; t1 *= inv; t2 *= inv; t3 *= inv;

    // broadcast each p-group's coef to the whole wave
    f32x4 cf0, cf1, cf2, cf3;
    cf0.x = __shfl(t0,  0); cf0.y = __shfl(t1,  0); cf0.z = __shfl(t2,  0); cf0.w = __shfl(t3,  0);
    cf1.x = __shfl(t0, 16); cf1.y = __shfl(t1, 16); cf1.z = __shfl(t2, 16); cf1.w = __shfl(t3, 16);
    cf2.x = __shfl(t0, 32); cf2.y = __shfl(t1, 32); cf2.z = __shfl(t2, 32); cf2.w = __shfl(t3, 32);
    cf3.x = __shfl(t0, 48); cf3.y = __shfl(t1, 48); cf3.z = __shfl(t2, 48); cf3.w = __shfl(t3, 48);

    // ---- R10's proven main body (bounds-checked gathers, NT stores) ----
    const int sl0 = sel[c * 8 + 0], sl1 = sel[c * 8 + 1];
    const int sl2 = sel[c * 8 + 2], sl3 = sel[c * 8 + 3];
    const int sl4 = sel[c * 8 + 4], sl5 = sel[c * 8 + 5];
    const int sl6 = sel[c * 8 + 6], sl7 = sel[c * 8 + 7];

    const int nbase = n * (C_IN * H_IN * W_IN);
    f32x4* __restrict__ yv = reinterpret_cast<f32x4*>(y) +
                             (size_t)(n * C_OUT + c) * (H_OUT * W_OUT);

    #pragma unroll
    for (int k = 0; k < 4; ++k) {
        const int pos = threadIdx.x + k * 256;   // 0..1023
        const int oh = pos >> 5;
        const int ow = pos & 31;

        float a, b;
        f32x4 out;

        a = gather_x(x, nbase, sl0, oh, ow);
        b = gather_x(x, nbase, sl1, oh, ow);
        out.x = fmaf(cf0.w * a, b, fmaf(cf0.y, a, fmaf(cf0.z, b, cf0.x)));

        a = gather_x(x, nbase, sl2, oh, ow);
        b = gather_x(x, nbase, sl3, oh, ow);
        out.y = fmaf(cf1.w * a, b, fmaf(cf1.y, a, fmaf(cf1.z, b, cf1.x)));

        a = gather_x(x, nbase, sl4, oh, ow);
        b = gather_x(x, nbase, sl5, oh, ow);
        out.z = fmaf(cf2.w * a, b, fmaf(cf2.y, a, fmaf(cf2.z, b, cf2.x)));

        a = gather_x(x, nbase, sl6, oh, ow);
        b = gather_x(x, nbase, sl7, oh, ow);
        out.w = fmaf(cf3.w * a, b, fmaf(cf3.y, a, fmaf(cf3.z, b, cf3.x)));

        // Write-once 268 MB stream: nontemporal so it doesn't churn L2.
        __builtin_nontemporal_store(out, &yv[pos]);
    }
}

extern "C" void kernel_launch(void* const* d_in, const int* in_sizes, int n_in,
                              void* d_out, int out_size, void* d_ws, size_t ws_size,
                              hipStream_t stream) {
    const float* x       = (const float*)d_in[0];
    const float* weights = (const float*)d_in[1];
    const int*   sel     = (const int*)d_in[2];
    float* y             = (float*)d_out;

    conv_logic_kernel<<<dim3(C_OUT, N_BATCH), 256, 0, stream>>>(x, weights, sel, y);
}

// Round 17
// 60.133 us; speedup vs baseline: 1.0576x; 1.0157x over previous
//
#include <hip/hip_runtime.h>

// Problem constants (fixed by setup_inputs)
#define N_BATCH 32
#define C_IN    64
#define H_IN    32
#define W_IN    32
#define C_OUT   512
#define H_OUT   32
#define W_OUT   32

typedef float f32x4 __attribute__((ext_vector_type(4)));

__device__ __forceinline__ float gather_x(const float* __restrict__ x,
                                          int nbase, int s, int oh, int ow) {
    int ch = (s >> 16) & 0xffff;
    int ry = (s >> 8) & 0xff;
    int rx = s & 0xff;
    int r = oh + ry - 1;          // PAD_H = 1
    int c = ow + rx - 1;          // PAD_W = 1
    bool ok = ((unsigned)r < (unsigned)H_IN) && ((unsigned)c < (unsigned)W_IN);
    return ok ? x[nbase + ch * (H_IN * W_IN) + r * W_IN + c] : 0.0f;
}

// Single kernel. The k=0 gather loads (which depend only on sel, not on the
// coefficients) and the weights load are issued BEFORE the shfl-reduce
// softmax prologue, so the prologue's ~300-500 cy of serial cross-lane work
// executes while the first memory round-trip is in flight. OP_COEFFS[i] is
// synthesized from the bits of i (multilinear expansion of the 16 gates):
// f00=(i>>3)&1, f01=(i>>2)&1, f10=(i>>1)&1, f11=i&1;
// k0=f00, ka=f10-f00, kb=f01-f00, kab=f11-f10-f01+f00. (Verified all 16 rows.)
__global__ __launch_bounds__(256)
void conv_logic_kernel(const float* __restrict__ x,
                       const float* __restrict__ weights,
                       const int*   __restrict__ sel,
                       float* __restrict__ y) {
    const int c = blockIdx.x;   // C_OUT
    const int n = blockIdx.y;   // N
    const int lane = threadIdx.x & 63;

    // --- scalar sel loads (s_load, ~free) ---
    const int sl0 = sel[c * 8 + 0], sl1 = sel[c * 8 + 1];
    const int sl2 = sel[c * 8 + 2], sl3 = sel[c * 8 + 3];
    const int sl4 = sel[c * 8 + 4], sl5 = sel[c * 8 + 5];
    const int sl6 = sel[c * 8 + 6], sl7 = sel[c * 8 + 7];

    const int nbase = n * (C_IN * H_IN * W_IN);

    // --- issue k=0 gathers + weights load FIRST (independent of coef) ---
    const int pos0 = threadIdx.x;
    const int oh0 = pos0 >> 5;
    const int ow0 = pos0 & 31;
    const float a0_0 = gather_x(x, nbase, sl0, oh0, ow0);
    const float b0_0 = gather_x(x, nbase, sl1, oh0, ow0);
    const float a1_0 = gather_x(x, nbase, sl2, oh0, ow0);
    const float b1_0 = gather_x(x, nbase, sl3, oh0, ow0);
    const float a2_0 = gather_x(x, nbase, sl4, oh0, ow0);
    const float b2_0 = gather_x(x, nbase, sl5, oh0, ow0);
    const float a3_0 = gather_x(x, nbase, sl6, oh0, ow0);
    const float b3_0 = gather_x(x, nbase, sl7, oh0, ow0);
    const float w = weights[c * 64 + lane];        // (c*4+p)*16+i == c*64+lane

    // --- wave-parallel softmax coef (runs under the loads' latency) ---
    const int i = lane & 15;
    float m = w;
    m = fmaxf(m, __shfl_xor(m, 1));
    m = fmaxf(m, __shfl_xor(m, 2));
    m = fmaxf(m, __shfl_xor(m, 4));
    m = fmaxf(m, __shfl_xor(m, 8));
    const float v = __expf(w - m);
    float ssum = v;
    ssum += __shfl_xor(ssum, 1);
    ssum += __shfl_xor(ssum, 2);
    ssum += __shfl_xor(ssum, 4);
    ssum += __shfl_xor(ssum, 8);
    const float inv = 1.0f / ssum;

    const float f00 = (float)((i >> 3) & 1);
    const float f01 = (float)((i >> 2) & 1);
    const float f10 = (float)((i >> 1) & 1);
    const float f11 = (float)(i & 1);

    float t0 = v * f00;
    float t1 = v * (f10 - f00);
    float t2 = v * (f01 - f00);
    float t3 = v * (f11 - f10 - f01 + f00);

    #define GSUM(t) t += __shfl_xor(t, 1); t += __shfl_xor(t, 2); \
                    t += __shfl_xor(t, 4); t += __shfl_xor(t, 8);
    GSUM(t0) GSUM(t1) GSUM(t2) GSUM(t3)
    #undef GSUM
    t0 *= inv; t1 *= inv; t2 *= inv; t3 *= inv;

    f32x4 cf0, cf1, cf2, cf3;
    cf0.x = __shfl(t0,  0); cf0.y = __shfl(t1,  0); cf0.z = __shfl(t2,  0); cf0.w = __shfl(t3,  0);
    cf1.x = __shfl(t0, 16); cf1.y = __shfl(t1, 16); cf1.z = __shfl(t2, 16); cf1.w = __shfl(t3, 16);
    cf2.x = __shfl(t0, 32); cf2.y = __shfl(t1, 32); cf2.z = __shfl(t2, 32); cf2.w = __shfl(t3, 32);
    cf3.x = __shfl(t0, 48); cf3.y = __shfl(t1, 48); cf3.z = __shfl(t2, 48); cf3.w = __shfl(t3, 48);

    f32x4* __restrict__ yv = reinterpret_cast<f32x4*>(y) +
                             (size_t)(n * C_OUT + c) * (H_OUT * W_OUT);

    // --- k=0: consume the pre-issued loads ---
    {
        f32x4 out;
        out.x = fmaf(cf0.w * a0_0, b0_0, fmaf(cf0.y, a0_0, fmaf(cf0.z, b0_0, cf0.x)));
        out.y = fmaf(cf1.w * a1_0, b1_0, fmaf(cf1.y, a1_0, fmaf(cf1.z, b1_0, cf1.x)));
        out.z = fmaf(cf2.w * a2_0, b2_0, fmaf(cf2.y, a2_0, fmaf(cf2.z, b2_0, cf2.x)));
        out.w = fmaf(cf3.w * a3_0, b3_0, fmaf(cf3.y, a3_0, fmaf(cf3.z, b3_0, cf3.x)));
        __builtin_nontemporal_store(out, &yv[pos0]);
    }

    // --- k=1..3: R10's proven body ---
    #pragma unroll
    for (int k = 1; k < 4; ++k) {
        const int pos = threadIdx.x + k * 256;
        const int oh = pos >> 5;
        const int ow = pos & 31;

        float a, b;
        f32x4 out;

        a = gather_x(x, nbase, sl0, oh, ow);
        b = gather_x(x, nbase, sl1, oh, ow);
        out.x = fmaf(cf0.w * a, b, fmaf(cf0.y, a, fmaf(cf0.z, b, cf0.x)));

        a = gather_x(x, nbase, sl2, oh, ow);
        b = gather_x(x, nbase, sl3, oh, ow);
        out.y = fmaf(cf1.w * a, b, fmaf(cf1.y, a, fmaf(cf1.z, b, cf1.x)));

        a = gather_x(x, nbase, sl4, oh, ow);
        b = gather_x(x, nbase, sl5, oh, ow);
        out.z = fmaf(cf2.w * a, b, fmaf(cf2.y, a, fmaf(cf2.z, b, cf2.x)));

        a = gather_x(x, nbase, sl6, oh, ow);
        b = gather_x(x, nbase, sl7, oh, ow);
        out.w = fmaf(cf3.w * a, b, fmaf(cf3.y, a, fmaf(cf3.z, b, cf3.x)));

        __builtin_nontemporal_store(out, &yv[pos]);
    }
}

extern "C" void kernel_launch(void* const* d_in, const int* in_sizes, int n_in,
                              void* d_out, int out_size, void* d_ws, size_t ws_size,
                              hipStream_t stream) {
    const float* x       = (const float*)d_in[0];
    const float* weights = (const float*)d_in[1];
    const int*   sel     = (const int*)d_in[2];
    float* y             = (float*)d_out;

    conv_logic_kernel<<<dim3(C_OUT, N_BATCH), 256, 0, stream>>>(x, weights, sel, y);
}

// Round 18
// 57.416 us; speedup vs baseline: 1.1077x; 1.0473x over previous
//
#include <hip/hip_runtime.h>

// Problem constants (fixed by setup_inputs)
#define N_BATCH 32
#define C_IN    64
#define H_IN    32
#define W_IN    32
#define C_OUT   512
#define H_OUT   32
#define W_OUT   32

typedef float f32x4 __attribute__((ext_vector_type(4)));

__device__ __forceinline__ void op_coeffs(int i, float& c0, float& c1, float& c2, float& c3) {
    constexpr float T[16][4] = {
        {0.f,0.f,0.f,0.f}, {0.f,0.f,0.f,1.f}, {0.f,1.f,0.f,-1.f}, {0.f,1.f,0.f,0.f},
        {0.f,0.f,1.f,-1.f}, {0.f,0.f,1.f,0.f}, {0.f,1.f,1.f,-2.f}, {0.f,1.f,1.f,-1.f},
        {1.f,-1.f,-1.f,1.f}, {1.f,-1.f,-1.f,2.f}, {1.f,0.f,-1.f,0.f}, {1.f,0.f,-1.f,1.f},
        {1.f,-1.f,0.f,0.f}, {1.f,-1.f,0.f,1.f}, {1.f,0.f,0.f,-1.f}, {1.f,0.f,0.f,0.f}
    };
    c0 = T[i][0]; c1 = T[i][1]; c2 = T[i][2]; c3 = T[i][3];
}

// ---------- kernel 1: coefficient table (512*4 entries -> d_ws, 32 KB) ----------
__global__ __launch_bounds__(256)
void coef_kernel(const float* __restrict__ weights, f32x4* __restrict__ coef) {
    const int idx = blockIdx.x * 256 + threadIdx.x;   // (c*4 + p), 0..2047
    if (idx >= C_OUT * 4) return;
    const float* w = weights + idx * 16;
    float v[16];
    float m = -3.402823466e+38f;
    #pragma unroll
    for (int i = 0; i < 16; ++i) { v[i] = w[i]; m = fmaxf(m, v[i]); }
    float ssum = 0.f;
    #pragma unroll
    for (int i = 0; i < 16; ++i) { v[i] = __expf(v[i] - m); ssum += v[i]; }
    const float inv = 1.0f / ssum;
    float c0 = 0.f, c1 = 0.f, c2 = 0.f, c3 = 0.f;
    #pragma unroll
    for (int i = 0; i < 16; ++i) {
        float t0, t1, t2, t3;
        op_coeffs(i, t0, t1, t2, t3);
        c0 = fmaf(v[i], t0, c0);
        c1 = fmaf(v[i], t1, c1);
        c2 = fmaf(v[i], t2, c2);
        c3 = fmaf(v[i], t3, c3);
    }
    f32x4 out; out.x = c0 * inv; out.y = c1 * inv; out.z = c2 * inv; out.w = c3 * inv;
    coef[idx] = out;
}

__device__ __forceinline__ float gather_x(const float* __restrict__ x,
                                          int nbase, int s, int oh, int ow) {
    int ch = (s >> 16) & 0xffff;
    int ry = (s >> 8) & 0xff;
    int rx = s & 0xff;
    int r = oh + ry - 1;          // PAD_H = 1
    int c = ow + rx - 1;          // PAD_W = 1
    bool ok = ((unsigned)r < (unsigned)H_IN) && ((unsigned)c < (unsigned)W_IN);
    return ok ? x[nbase + ch * (H_IN * W_IN) + r * W_IN + c] : 0.0f;
}

// ---------- kernel 2: main stream — no LDS, no __syncthreads ----------
// coef/sel loads are block-uniform (blockIdx-based address) -> scalar s_load;
// waves begin gather/store immediately, no prologue barrier to expose.
__global__ __launch_bounds__(256)
void conv_main_kernel(const float* __restrict__ x,
                      const f32x4* __restrict__ coef,
                      const int*   __restrict__ sel,
                      float* __restrict__ y) {
    const int c = blockIdx.x;   // C_OUT
    const int n = blockIdx.y;   // N

    // Block-uniform scalar loads (L2-resident: sel 16KB, coef 32KB).
    const int sl0 = sel[c * 8 + 0], sl1 = sel[c * 8 + 1];
    const int sl2 = sel[c * 8 + 2], sl3 = sel[c * 8 + 3];
    const int sl4 = sel[c * 8 + 4], sl5 = sel[c * 8 + 5];
    const int sl6 = sel[c * 8 + 6], sl7 = sel[c * 8 + 7];
    const f32x4 cf0 = coef[c * 4 + 0];
    const f32x4 cf1 = coef[c * 4 + 1];
    const f32x4 cf2 = coef[c * 4 + 2];
    const f32x4 cf3 = coef[c * 4 + 3];

    const int nbase = n * (C_IN * H_IN * W_IN);
    f32x4* __restrict__ yv = reinterpret_cast<f32x4*>(y) +
                             (size_t)(n * C_OUT + c) * (H_OUT * W_OUT);

    #pragma unroll
    for (int k = 0; k < 4; ++k) {
        const int pos = threadIdx.x + k * 256;   // 0..1023
        const int oh = pos >> 5;
        const int ow = pos & 31;

        float a, b;
        f32x4 out;

        a = gather_x(x, nbase, sl0, oh, ow);
        b = gather_x(x, nbase, sl1, oh, ow);
        out.x = fmaf(cf0.w * a, b, fmaf(cf0.y, a, fmaf(cf0.z, b, cf0.x)));

        a = gather_x(x, nbase, sl2, oh, ow);
        b = gather_x(x, nbase, sl3, oh, ow);
        out.y = fmaf(cf1.w * a, b, fmaf(cf1.y, a, fmaf(cf1.z, b, cf1.x)));

        a = gather_x(x, nbase, sl4, oh, ow);
        b = gather_x(x, nbase, sl5, oh, ow);
        out.z = fmaf(cf2.w * a, b, fmaf(cf2.y, a, fmaf(cf2.z, b, cf2.x)));

        a = gather_x(x, nbase, sl6, oh, ow);
        b = gather_x(x, nbase, sl7, oh, ow);
        out.w = fmaf(cf3.w * a, b, fmaf(cf3.y, a, fmaf(cf3.z, b, cf3.x)));

        // Write-once 268 MB stream: nontemporal, don't churn L2.
        __builtin_nontemporal_store(out, &yv[pos]);
    }
}

// ---------- fused fallback (only if d_ws is too small; R8 structure) ----------
__global__ __launch_bounds__(256)
void conv_fused_kernel(const float* __restrict__ x,
                       const float* __restrict__ weights,
                       const int*   __restrict__ sel,
                       float* __restrict__ y) {
    const int c = blockIdx.x;
    const int n = blockIdx.y;

    __shared__ float4 s_coef[4];
    __shared__ int    s_sel[8];

    if (threadIdx.x < 8) s_sel[threadIdx.x] = sel[c * 8 + threadIdx.x];
    if (threadIdx.x < 4) {
        const int p = threadIdx.x;
        const float* w = weights + (c * 4 + p) * 16;
        float v[16];
        float m = -3.402823466e+38f;
        #pragma unroll
        for (int i = 0; i < 16; ++i) { v[i] = w[i]; m = fmaxf(m, v[i]); }
        float ssum = 0.f;
        #pragma unroll
        for (int i = 0; i < 16; ++i) { v[i] = __expf(v[i] - m); ssum += v[i]; }
        const float inv = 1.0f / ssum;
        float c0 = 0.f, c1 = 0.f, c2 = 0.f, c3 = 0.f;
        #pragma unroll
        for (int i = 0; i < 16; ++i) {
            float t0, t1, t2, t3;
            op_coeffs(i, t0, t1, t2, t3);
            c0 = fmaf(v[i], t0, c0);
            c1 = fmaf(v[i], t1, c1);
            c2 = fmaf(v[i], t2, c2);
            c3 = fmaf(v[i], t3, c3);
        }
        s_coef[p] = make_float4(c0 * inv, c1 * inv, c2 * inv, c3 * inv);
    }
    __syncthreads();

    const int nbase = n * (C_IN * H_IN * W_IN);
    f32x4* __restrict__ yv = reinterpret_cast<f32x4*>(y) +
                             (size_t)(n * C_OUT + c) * (H_OUT * W_OUT);

    const float4 cf0 = s_coef[0], cf1 = s_coef[1], cf2 = s_coef[2], cf3 = s_coef[3];
    const int sl0 = s_sel[0], sl1 = s_sel[1], sl2 = s_sel[2], sl3 = s_sel[3];
    const int sl4 = s_sel[4], sl5 = s_sel[5], sl6 = s_sel[6], sl7 = s_sel[7];

    #pragma unroll
    for (int k = 0; k < 4; ++k) {
        const int pos = threadIdx.x + k * 256;
        const int oh = pos >> 5;
        const int ow = pos & 31;
        float a, b;
        f32x4 out;
        a = gather_x(x, nbase, sl0, oh, ow);
        b = gather_x(x, nbase, sl1, oh, ow);
        out.x = fmaf(cf0.w * a, b, fmaf(cf0.y, a, fmaf(cf0.z, b, cf0.x)));
        a = gather_x(x, nbase, sl2, oh, ow);
        b = gather_x(x, nbase, sl3, oh, ow);
        out.y = fmaf(cf1.w * a, b, fmaf(cf1.y, a, fmaf(cf1.z, b, cf1.x)));
        a = gather_x(x, nbase, sl4, oh, ow);
        b = gather_x(x, nbase, sl5, oh, ow);
        out.z = fmaf(cf2.w * a, b, fmaf(cf2.y, a, fmaf(cf2.z, b, cf2.x)));
        a = gather_x(x, nbase, sl6, oh, ow);
        b = gather_x(x, nbase, sl7, oh, ow);
        out.w = fmaf(cf3.w * a, b, fmaf(cf3.y, a, fmaf(cf3.z, b, cf3.x)));
        __builtin_nontemporal_store(out, &yv[pos]);
    }
}

extern "C" void kernel_launch(void* const* d_in, const int* in_sizes, int n_in,
                              void* d_out, int out_size, void* d_ws, size_t ws_size,
                              hipStream_t stream) {
    const float* x       = (const float*)d_in[0];
    const float* weights = (const float*)d_in[1];
    const int*   sel     = (const int*)d_in[2];
    float* y             = (float*)d_out;

    const size_t coef_bytes = (size_t)C_OUT * 4 * sizeof(f32x4);   // 32 KB
    dim3 grid(C_OUT, N_BATCH);

    if (ws_size >= coef_bytes) {
        f32x4* coef = (f32x4*)d_ws;
        coef_kernel<<<dim3((C_OUT * 4 + 255) / 256), 256, 0, stream>>>(weights, coef);
        conv_main_kernel<<<grid, 256, 0, stream>>>(x, coef, sel, y);
    } else {
        conv_fused_kernel<<<grid, 256, 0, stream>>>(x, weights, sel, y);
    }
}